// Round 2
// baseline (137.174 us; speedup 1.0000x reference)
//
#include <hip/hip_runtime.h>
#include <math.h>

#define HDIM 128

// ---------------------------------------------------------------------------
// segment_ids is sorted: starts[s] = first t with seg[t] >= s.
// Boundary thread t (seg[t-1] != seg[t]) fills starts for the covered range.
// Thread T-1 fills trailing empty segments with T; thread 0 zeroes the loss.
// (init kernel fused away.)
// ---------------------------------------------------------------------------
__global__ __launch_bounds__(256) void seg_bounds_kernel(
    const int* __restrict__ seg, int* __restrict__ starts,
    int Tval, int Bval, float* __restrict__ out) {
    int t = blockIdx.x * blockDim.x + threadIdx.x;
    if (t >= Tval) return;
    int b = seg[t];
    int a = (t == 0) ? -1 : seg[t - 1];
    for (int s = a + 1; s <= b; ++s) starts[s] = t;
    if (t == Tval - 1) {
        for (int s = b + 1; s <= Bval; ++s) starts[s] = Tval;
    }
    if (t == 0) out[0] = 0.0f;
}

// ---------------------------------------------------------------------------
// Gather + segment-mean. TWO waves per segment (parity-split token streams)
// -> 8192 waves = 32 waves/CU (full occupancy) for latency hiding.
// Within a wave, half-wave h (32 lanes) covers one token per row-load instr
// (512 B coalesced, float4/lane). Streams: q = parity*2 + half, stride 4.
// 4-deep unroll + software-pipelined token-id prefetch: the next iter's ids
// load while the current row loads are in flight (no serial id->row chain).
// Parity partials combine through LDS; parity-0 wave scales and stores.
// ---------------------------------------------------------------------------
__global__ __launch_bounds__(256) void gather_mean_kernel(
    const int* __restrict__ tok, const float* __restrict__ emb,
    const int* __restrict__ starts, float* __restrict__ sent, int Bval) {
    __shared__ float4 part[2][32];   // parity-1 partial per segment slot

    int wave = threadIdx.x >> 6;
    int lane = threadIdx.x & 63;
    int segslot = wave >> 1;         // 0..1: which segment of this block
    int parity  = wave & 1;          // 0..1: which token-parity stream
    int s = blockIdx.x * 2 + segslot;
    if (s >= Bval) s = Bval - 1;     // clamp: duplicate work, identical writes

    int t0 = starts[s];
    int t1 = starts[s + 1];
    int cnt = t1 - t0;

    int half = lane >> 5;
    int col  = lane & 31;            // float4 column within the 128-f row
    int q = parity * 2 + half;       // stream id 0..3, stride 4 over tokens

    float4 acc = make_float4(0.f, 0.f, 0.f, 0.f);

    int i = t0 + q;
    if (i + 12 < t1) {
        int ta = tok[i], tb = tok[i + 4], tc = tok[i + 8], td = tok[i + 12];
        for (;;) {
            float4 fa = ((const float4*)(emb + (size_t)ta * HDIM))[col];
            float4 fb = ((const float4*)(emb + (size_t)tb * HDIM))[col];
            float4 fc = ((const float4*)(emb + (size_t)tc * HDIM))[col];
            float4 fd = ((const float4*)(emb + (size_t)td * HDIM))[col];
            int ni = i + 16;
            bool more = (ni + 12 < t1);
            if (more) {   // prefetch next ids before the rows' vmcnt wait
                ta = tok[ni]; tb = tok[ni + 4]; tc = tok[ni + 8]; td = tok[ni + 12];
            }
            acc.x += fa.x + fb.x + fc.x + fd.x;
            acc.y += fa.y + fb.y + fc.y + fd.y;
            acc.z += fa.z + fb.z + fc.z + fd.z;
            acc.w += fa.w + fb.w + fc.w + fd.w;
            i = ni;
            if (!more) break;
        }
    }
    for (; i < t1; i += 4) {         // tail: one token per stream step
        int tt = tok[i];
        float4 f = ((const float4*)(emb + (size_t)tt * HDIM))[col];
        acc.x += f.x; acc.y += f.y; acc.z += f.z; acc.w += f.w;
    }

    // combine the two half-waves: all lanes end with the wave's stream-pair sum
    acc.x += __shfl_xor(acc.x, 32);
    acc.y += __shfl_xor(acc.y, 32);
    acc.z += __shfl_xor(acc.z, 32);
    acc.w += __shfl_xor(acc.w, 32);

    if (parity == 1 && half == 0) part[segslot][col] = acc;
    __syncthreads();
    if (parity == 0 && half == 0) {
        float4 o = part[segslot][col];
        acc.x += o.x; acc.y += o.y; acc.z += o.z; acc.w += o.w;
        float inv = 1.0f / (float)(cnt > 0 ? cnt : 1);
        acc.x *= inv; acc.y *= inv; acc.z *= inv; acc.w *= inv;
        ((float4*)(sent + (size_t)s * HDIM))[col] = acc;
    }
}

// ---------------------------------------------------------------------------
// MLP head + BCE loss. W_hid (64 KB) staged once per block in LDS.
// Each wave register-blocks 4 segments: per k-step 1 ds_read_b64 (W pair) +
// 4 broadcast reads (sent) + 8 FMAs. Lane l owns output columns 2l, 2l+1.
// Output dot (W_out) via 64-lane shfl_xor reduce; one atomicAdd per block.
// ---------------------------------------------------------------------------
__global__ __launch_bounds__(256) void mlp_loss_kernel(
    const float* __restrict__ sent, const float* __restrict__ Wh,
    const float* __restrict__ bh, const float* __restrict__ Wo,
    const float* __restrict__ bo, const float* __restrict__ y,
    float* __restrict__ out, int Bval, int nblocks) {
    __shared__ float Wlds[HDIM * HDIM];       // 64 KB
    __shared__ float slds[4][4 * HDIM];       // 8 KB: 4 waves x 4 segments
    __shared__ float lred[4];

    for (int idx = threadIdx.x; idx < HDIM * HDIM / 4; idx += 256)
        ((float4*)Wlds)[idx] = ((const float4*)Wh)[idx];
    __syncthreads();

    int wave = threadIdx.x >> 6;
    int lane = threadIdx.x & 63;
    int j0 = lane * 2;

    float bh0 = bh[j0], bh1 = bh[j0 + 1];
    float wo0 = Wo[j0], wo1 = Wo[j0 + 1];
    float bov = bo[0];
    float lsum = 0.0f;

    const float2* W2 = (const float2*)Wlds;
    float* myld = &slds[wave][0];

    for (int base0 = blockIdx.x * 16; base0 < Bval; base0 += nblocks * 16) {
        int base = base0 + wave * 4;
        int rem = Bval - base;
        int nseg = rem < 4 ? (rem < 0 ? 0 : rem) : 4;

        for (int r = 0; r < nseg; ++r) {
            float2 v = ((const float2*)(sent + (size_t)(base + r) * HDIM))[lane];
            ((float2*)(myld + r * HDIM))[lane] = v;
        }
        // same-wave LDS RAW: compiler inserts lgkmcnt waits.

        float a00 = bh0, a01 = bh1, a10 = bh0, a11 = bh1;
        float a20 = bh0, a21 = bh1, a30 = bh0, a31 = bh1;
        for (int i = 0; i < HDIM; ++i) {
            float2 w = W2[i * (HDIM / 2) + lane];
            float s0 = myld[0 * HDIM + i];
            float s1 = myld[1 * HDIM + i];
            float s2 = myld[2 * HDIM + i];
            float s3 = myld[3 * HDIM + i];
            a00 = fmaf(s0, w.x, a00); a01 = fmaf(s0, w.y, a01);
            a10 = fmaf(s1, w.x, a10); a11 = fmaf(s1, w.y, a11);
            a20 = fmaf(s2, w.x, a20); a21 = fmaf(s2, w.y, a21);
            a30 = fmaf(s3, w.x, a30); a31 = fmaf(s3, w.y, a31);
        }

        float pr0 = tanhf(a00) * wo0 + tanhf(a01) * wo1;
        float pr1 = tanhf(a10) * wo0 + tanhf(a11) * wo1;
        float pr2 = tanhf(a20) * wo0 + tanhf(a21) * wo1;
        float pr3 = tanhf(a30) * wo0 + tanhf(a31) * wo1;
        for (int m = 1; m < 64; m <<= 1) {
            pr0 += __shfl_xor(pr0, m);
            pr1 += __shfl_xor(pr1, m);
            pr2 += __shfl_xor(pr2, m);
            pr3 += __shfl_xor(pr3, m);
        }

        if (lane == 0) {
            float prs[4] = {pr0, pr1, pr2, pr3};
            for (int r = 0; r < nseg; ++r) {
                float z = prs[r] + bov;
                float p = 1.0f / (1.0f + expf(-z));
                float lp  = fmaxf(logf(p),     -100.0f);
                float l1p = fmaxf(log1pf(-p),  -100.0f);
                float yv = y[base + r];
                lsum -= yv * lp + (1.0f - yv) * l1p;
            }
        }
    }

    if (lane == 0) lred[wave] = lsum;
    __syncthreads();
    if (threadIdx.x == 0) {
        float tot = lred[0] + lred[1] + lred[2] + lred[3];
        atomicAdd(out, tot);
    }
}

// ---------------------------------------------------------------------------
extern "C" void kernel_launch(void* const* d_in, const int* in_sizes, int n_in,
                              void* d_out, int out_size, void* d_ws, size_t ws_size,
                              hipStream_t stream) {
    const int*   tok = (const int*)d_in[0];
    const int*   seg = (const int*)d_in[1];
    const float* y   = (const float*)d_in[2];
    const float* emb = (const float*)d_in[3];
    const float* Wh  = (const float*)d_in[4];
    const float* bh  = (const float*)d_in[5];
    const float* Wo  = (const float*)d_in[6];
    const float* bo  = (const float*)d_in[7];

    int T_ = in_sizes[0];
    int B_ = in_sizes[2];

    float* out = (float*)d_out;

    // ws layout: starts[B+1] ints (aligned to 256 B), then sent[B*H] floats.
    int* starts = (int*)d_ws;
    size_t starts_bytes = ((size_t)(B_ + 1) * sizeof(int) + 255) & ~(size_t)255;
    float* sent = (float*)((char*)d_ws + starts_bytes);

    seg_bounds_kernel<<<(T_ + 255) / 256, 256, 0, stream>>>(seg, starts, T_, B_, out);
    gather_mean_kernel<<<(B_ + 1) / 2, 256, 0, stream>>>(tok, emb, starts, sent, B_);
    int nblocks = (B_ + 15) / 16;
    if (nblocks > 256) nblocks = 256;
    mlp_loss_kernel<<<nblocks, 256, 0, stream>>>(sent, Wh, bh, Wo, bo, y, out, B_, nblocks);
}